// Round 1
// 3621.409 us; speedup vs baseline: 1.8011x; 1.8011x over previous
//
#include <hip/hip_runtime.h>
#include <hip/hip_bf16.h>

// Swin block, fixed shapes: B=8, H=W=224, C=192, WS=7, SHIFT=3, NH=6, HD=32, DFF=768
// Kernel prep: transpose qkv_w/proj_w/w1/w2 to bf16 [n][k] layout in d_ws.
// Kernel A (REWRITTEN, MFMA): per-(batch,window) fused LN1 + QKV + attention + proj + residual,
//   all four GEMMs on mfma_f32_16x16x32_bf16, in-register softmax, f32 accumulation.
// Kernel B (unchanged): 32 tokens/block, LN2 + GEMM1(MFMA bf16) + GELU + GEMM2(MFMA bf16) + residual.

#define CDIM 192
#define NH6 6
#define HD32 32
#define NTOK 49
#define DFFX 768
#define HW224 224
#define LTOK 50176

typedef __bf16 bf16x8 __attribute__((ext_vector_type(8)));
typedef float  f32x4  __attribute__((ext_vector_type(4)));

__device__ __forceinline__ int region_id(int p) {
    return (p < 217) ? 0 : ((p < 221) ? 1 : 2);
}

// ---- attention: one window per block, 4 waves = 4 M-tiles (rows of 16, tokens padded 49->64) ----
__global__ __launch_bounds__(256) void attn_kernel(
    const float* __restrict__ x,
    const __bf16* __restrict__ qkvt, const float* __restrict__ qkv_b,
    const __bf16* __restrict__ projt, const float* __restrict__ proj_b,
    const float* __restrict__ rpb,
    const float* __restrict__ n1w, const float* __restrict__ n1b,
    float* __restrict__ y)
{
    // LDS strides: multiples of 16B (b128 alignment), even bank coverage (8 dwords/bank).
    __shared__ __attribute__((aligned(16))) __bf16 xn[64][200];   // 25600 B  LN output, rows >=49 zero
    __shared__ __attribute__((aligned(16))) __bf16 Rbuf[5120];    // 10240 B  union: {qh|kh} / ps / oh
    __shared__ __attribute__((aligned(16))) __bf16 vt[32][72];    //  4608 B  V transposed [hd][token]
    __shared__ int regid[NTOK];

    __bf16 (* const qh)[40] = (__bf16 (*)[40])Rbuf;               // [64][40]
    __bf16 (* const kh)[40] = (__bf16 (*)[40])(Rbuf + 2560);      // [64][40]
    __bf16 (* const ps)[72] = (__bf16 (*)[72])Rbuf;               // [64][72] (overlaps qh+kh)
    __bf16 (* const oh)[40] = (__bf16 (*)[40])Rbuf;               // [64][40] (overlaps qh)

    const int tid = threadIdx.x;
    const int b  = blockIdx.x >> 10;
    const int w  = blockIdx.x & 1023;
    const int wr = w >> 5, wc = w & 31;
    const int wv = tid >> 6, lane = tid & 63;
    const int ln = lane & 15, quad = lane >> 4;

    if (tid < NTOK) {
        int r = tid / 7, cn = tid % 7;
        regid[tid] = region_id(wr*7 + r)*3 + region_id(wc*7 + cn);
    }

    // ---- LN1 -> xn (bf16); one wave per token ----
    for (int n = wv; n < NTOK; n += 4) {
        int r = n / 7, cn = n % 7;
        int hh = (wr*7 + r + 3) % HW224;
        int ww = (wc*7 + cn + 3) % HW224;
        const float* xp = x + ((size_t)b * LTOK + hh*HW224 + ww) * CDIM;
        float v0 = xp[lane], v1 = xp[lane+64], v2 = xp[lane+128];
        float s = v0+v1+v2, s2 = v0*v0+v1*v1+v2*v2;
        #pragma unroll
        for (int off = 32; off > 0; off >>= 1) {
            s  += __shfl_down(s, off);
            s2 += __shfl_down(s2, off);
        }
        s = __shfl(s, 0); s2 = __shfl(s2, 0);
        float mean = s * (1.0f/CDIM);
        float var  = s2 * (1.0f/CDIM) - mean*mean;
        float rstd = rsqrtf(var + 1e-5f);
        xn[n][lane]     = (__bf16)((v0-mean)*rstd*n1w[lane]     + n1b[lane]);
        xn[n][lane+64]  = (__bf16)((v1-mean)*rstd*n1w[lane+64]  + n1b[lane+64]);
        xn[n][lane+128] = (__bf16)((v2-mean)*rstd*n1w[lane+128] + n1b[lane+128]);
    }
    for (int i = tid; i < 15*CDIM; i += 256) xn[NTOK + i/CDIM][i%CDIM] = (__bf16)0.0f;
    __syncthreads();

    f32x4 pacc[12];
    #pragma unroll
    for (int j = 0; j < 12; ++j) pacc[j] = (f32x4){0.f,0.f,0.f,0.f};

    const float qscale = 0.17677669529663689f;
    const f32x4 z4 = (f32x4){0.f,0.f,0.f,0.f};

    for (int h = 0; h < NH6; ++h) {
        // ---- QKV GEMM: A = xn rows of this wave's M-tile; N = 96 cols {q0,q1,k0,k1,v0,v1} ----
        f32x4 aq[6];
        #pragma unroll
        for (int j = 0; j < 6; ++j) aq[j] = z4;
        const __bf16* bp[6];
        #pragma unroll
        for (int nt = 0; nt < 6; ++nt) {
            int wcol = (nt>>1)*192 + h*32 + (nt&1)*16 + ln;
            bp[nt] = qkvt + (size_t)wcol*192 + quad*8;
        }
        #pragma unroll
        for (int ks = 0; ks < 6; ++ks) {
            bf16x8 a = *(const bf16x8*)&xn[wv*16+ln][ks*32 + quad*8];
            #pragma unroll
            for (int nt = 0; nt < 6; ++nt) {
                bf16x8 bb = *(const bf16x8*)(bp[nt] + ks*32);
                aq[nt] = __builtin_amdgcn_mfma_f32_16x16x32_bf16(a, bb, aq[nt], 0, 0, 0);
            }
        }
        __syncthreads();   // prior head's oh/vt/ps reads complete before overwrite
        #pragma unroll
        for (int nt = 0; nt < 6; ++nt) {
            int part = nt>>1, sub = nt&1;
            float bias = qkv_b[part*192 + h*32 + sub*16 + ln];
            #pragma unroll
            for (int r = 0; r < 4; ++r) {
                int row = wv*16 + quad*4 + r;
                float v = aq[nt][r] + bias;
                if (part == 0)      qh[row][sub*16+ln] = (__bf16)(v*qscale);
                else if (part == 1) kh[row][sub*16+ln] = (__bf16)v;
                else                vt[sub*16+ln][row] = (__bf16)v;
            }
        }
        __syncthreads();

        // ---- S = Q.K^T (K=32, one MFMA K-step), 4 N-tiles ----
        f32x4 sa[4];
        {
            bf16x8 a = *(const bf16x8*)&qh[wv*16+ln][quad*8];
            #pragma unroll
            for (int nt = 0; nt < 4; ++nt) {
                bf16x8 bb = *(const bf16x8*)&kh[nt*16+ln][quad*8];
                sa[nt] = __builtin_amdgcn_mfma_f32_16x16x32_bf16(a, bb, z4, 0, 0, 0);
            }
        }
        // ---- bias + mask + in-register softmax (rows owned by 16-lane groups) ----
        float pr[4][4];
        #pragma unroll
        for (int r = 0; r < 4; ++r) {
            int row = wv*16 + quad*4 + r;
            int rq = row < NTOK ? row : 0;
            int r7 = rq/7, rm7 = rq - r7*7;
            int rreg = regid[rq];
            float rowmax = -3.0e30f;
            #pragma unroll
            for (int nt = 0; nt < 4; ++nt) {
                int col = nt*16 + ln;
                int cc = col < NTOK ? col : 0;
                int c7 = cc/7, cm7 = cc - c7*7;
                float sv = sa[nt][r] + rpb[((r7-c7+6)*13 + (rm7-cm7+6))*NH6 + h];
                if (regid[cc] != rreg) sv -= 100.f;
                if (col >= NTOK) sv = -1.0e30f;     // mask padding columns
                pr[nt][r] = sv;
                rowmax = fmaxf(rowmax, sv);
            }
            #pragma unroll
            for (int m = 1; m < 16; m <<= 1) rowmax = fmaxf(rowmax, __shfl_xor(rowmax, m));
            float sum = 0.f;
            #pragma unroll
            for (int nt = 0; nt < 4; ++nt) {
                float e = __expf(pr[nt][r] - rowmax);
                pr[nt][r] = e; sum += e;
            }
            #pragma unroll
            for (int m = 1; m < 16; m <<= 1) sum += __shfl_xor(sum, m);
            float inv = 1.0f / sum;
            #pragma unroll
            for (int nt = 0; nt < 4; ++nt) pr[nt][r] *= inv;
        }
        __syncthreads();   // all waves done reading qh/kh before ps overwrites them
        #pragma unroll
        for (int r = 0; r < 4; ++r) {
            int row = wv*16 + quad*4 + r;
            #pragma unroll
            for (int nt = 0; nt < 4; ++nt) ps[row][nt*16+ln] = (__bf16)pr[nt][r];
        }
        __syncthreads();

        // ---- O = P.V (K=64 incl. zero-P padding cols) ----
        f32x4 ov[2];
        #pragma unroll
        for (int j = 0; j < 2; ++j) ov[j] = z4;
        #pragma unroll
        for (int ks = 0; ks < 2; ++ks) {
            bf16x8 a = *(const bf16x8*)&ps[wv*16+ln][ks*32 + quad*8];
            #pragma unroll
            for (int nt = 0; nt < 2; ++nt) {
                bf16x8 bb = *(const bf16x8*)&vt[nt*16+ln][ks*32 + quad*8];
                ov[nt] = __builtin_amdgcn_mfma_f32_16x16x32_bf16(a, bb, ov[nt], 0, 0, 0);
            }
        }
        __syncthreads();   // all waves done reading ps/vt before oh overwrites
        #pragma unroll
        for (int nt = 0; nt < 2; ++nt)
            #pragma unroll
            for (int r = 0; r < 4; ++r)
                oh[wv*16 + quad*4 + r][nt*16+ln] = (__bf16)ov[nt][r];
        __syncthreads();

        // ---- proj partial GEMM: this head contributes K=32; accumulate across heads ----
        {
            bf16x8 a = *(const bf16x8*)&oh[wv*16+ln][quad*8];
            #pragma unroll
            for (int nt = 0; nt < 12; ++nt) {
                bf16x8 bb = *(const bf16x8*)(projt + (size_t)(nt*16+ln)*192 + h*32 + quad*8);
                pacc[nt] = __builtin_amdgcn_mfma_f32_16x16x32_bf16(a, bb, pacc[nt], 0, 0, 0);
            }
        }
        // loop-top barrier (after next QKV MFMAs) protects oh before qh overwrite
    }

    // ---- epilogue: y = x + proj + proj_b (rows >=49 discarded) ----
    #pragma unroll
    for (int r = 0; r < 4; ++r) {
        int row = wv*16 + quad*4 + r;
        if (row < NTOK) {
            int hh = (wr*7 + row/7 + 3) % HW224;
            int ww = (wc*7 + row%7 + 3) % HW224;
            size_t base = ((size_t)b * LTOK + hh*HW224 + ww) * CDIM;
            #pragma unroll
            for (int nt = 0; nt < 12; ++nt) {
                int c = nt*16 + ln;
                y[base + c] = x[base + c] + pacc[nt][r] + proj_b[c];
            }
        }
    }
}

// ---- weight prep: all weights -> bf16 [n][k] transposed layouts in d_ws ----
__global__ __launch_bounds__(256) void prep_kernel(
    const float* __restrict__ qkv_w, const float* __restrict__ proj_w,
    const float* __restrict__ w1, const float* __restrict__ w2,
    __bf16* __restrict__ qkvt, __bf16* __restrict__ projt,
    __bf16* __restrict__ w1t, __bf16* __restrict__ w2t)
{
    int i = blockIdx.x * 256 + threadIdx.x;
    if (i < 192*768) {
        int k1 = i / 768, n1 = i % 768;
        w1t[n1*192 + k1] = (__bf16)w1[i];
        int k2 = i / 192, n2 = i % 192;
        w2t[n2*768 + k2] = (__bf16)w2[i];
    }
    if (i < 192*576) {
        int k = i / 576, n = i % 576;
        qkvt[n*192 + k] = (__bf16)qkv_w[i];
    }
    if (i < 192*192) {
        int k = i / 192, n = i % 192;
        projt[n*192 + k] = (__bf16)proj_w[i];
    }
}

// ---- MLP: 32 tokens/block, MFMA bf16 16x16x32 (unchanged) ----
#define XPAD 200   // 192+8: row stride 400B -> 2-way LDS alias (free)
#define HPAD 776   // 768+8: row stride 1552B -> 2-way LDS alias (free)

__global__ __launch_bounds__(256) void mlp_kernel(
    float* __restrict__ y,
    const float* __restrict__ n2w, const float* __restrict__ n2b,
    const __bf16* __restrict__ w1t, const float* __restrict__ b1,
    const __bf16* __restrict__ w2t, const float* __restrict__ b2)
{
    __shared__ __attribute__((aligned(16))) __bf16 xnb[32][XPAD];  // 12,800 B
    __shared__ __attribute__((aligned(16))) __bf16 hid[32][HPAD];  // 49,664 B (total 62,464)

    const int tid = threadIdx.x;
    const int wv = tid >> 6, lane = tid & 63;
    const int ln = lane & 15, quad = lane >> 4;
    const size_t g0 = (size_t)blockIdx.x * 32;

    // ---- LN2: one wave per token ----
    for (int t = wv; t < 32; t += 4) {
        const float* xp = y + (g0 + t) * CDIM;
        float v0 = xp[lane], v1 = xp[lane+64], v2 = xp[lane+128];
        float s = v0+v1+v2, s2 = v0*v0+v1*v1+v2*v2;
        #pragma unroll
        for (int off = 32; off > 0; off >>= 1) {
            s  += __shfl_down(s, off);
            s2 += __shfl_down(s2, off);
        }
        s = __shfl(s, 0); s2 = __shfl(s2, 0);
        float mean = s * (1.0f/CDIM);
        float var  = s2 * (1.0f/CDIM) - mean*mean;
        float rstd = rsqrtf(var + 1e-5f);
        xnb[t][lane]     = (__bf16)((v0-mean)*rstd*n2w[lane]     + n2b[lane]);
        xnb[t][lane+64]  = (__bf16)((v1-mean)*rstd*n2w[lane+64]  + n2b[lane+64]);
        xnb[t][lane+128] = (__bf16)((v2-mean)*rstd*n2w[lane+128] + n2b[lane+128]);
    }
    __syncthreads();

    // ---- GEMM1 + GELU -> hid ----
    {
        f32x4 acc[2][12];
        #pragma unroll
        for (int mt = 0; mt < 2; ++mt)
            #pragma unroll
            for (int j = 0; j < 12; ++j) acc[mt][j] = (f32x4){0.f,0.f,0.f,0.f};

        for (int ks = 0; ks < 6; ++ks) {           // K = 6 * 32
            const int kb = ks*32 + quad*8;
            bf16x8 a0 = *(const bf16x8*)&xnb[ln][kb];
            bf16x8 a1 = *(const bf16x8*)&xnb[16+ln][kb];
            #pragma unroll
            for (int j = 0; j < 12; ++j) {
                const int nt = wv*12 + j;
                bf16x8 bfr = *(const bf16x8*)(w1t + (size_t)(nt*16 + ln)*192 + kb);
                acc[0][j] = __builtin_amdgcn_mfma_f32_16x16x32_bf16(a0, bfr, acc[0][j], 0, 0, 0);
                acc[1][j] = __builtin_amdgcn_mfma_f32_16x16x32_bf16(a1, bfr, acc[1][j], 0, 0, 0);
            }
        }
        #pragma unroll
        for (int j = 0; j < 12; ++j) {
            const int c = (wv*12 + j)*16 + ln;
            const float bias = b1[c];
            #pragma unroll
            for (int mt = 0; mt < 2; ++mt) {
                #pragma unroll
                for (int r = 0; r < 4; ++r) {
                    int t = mt*16 + quad*4 + r;
                    float v = acc[mt][j][r] + bias;
                    hid[t][c] = (__bf16)(0.5f*v*(1.0f + erff(v*0.70710678118654752f)));
                }
            }
        }
    }
    __syncthreads();

    // ---- GEMM2 + residual ----
    {
        f32x4 acc[2][3];
        #pragma unroll
        for (int mt = 0; mt < 2; ++mt)
            #pragma unroll
            for (int j = 0; j < 3; ++j) acc[mt][j] = (f32x4){0.f,0.f,0.f,0.f};

        for (int ks = 0; ks < 24; ++ks) {          // K = 24 * 32
            const int kb = ks*32 + quad*8;
            bf16x8 a0 = *(const bf16x8*)&hid[ln][kb];
            bf16x8 a1 = *(const bf16x8*)&hid[16+ln][kb];
            #pragma unroll
            for (int j = 0; j < 3; ++j) {
                const int nt = wv*3 + j;
                bf16x8 bfr = *(const bf16x8*)(w2t + (size_t)(nt*16 + ln)*768 + kb);
                acc[0][j] = __builtin_amdgcn_mfma_f32_16x16x32_bf16(a0, bfr, acc[0][j], 0, 0, 0);
                acc[1][j] = __builtin_amdgcn_mfma_f32_16x16x32_bf16(a1, bfr, acc[1][j], 0, 0, 0);
            }
        }
        #pragma unroll
        for (int j = 0; j < 3; ++j) {
            const int c = (wv*3 + j)*16 + ln;
            const float bias = b2[c];
            #pragma unroll
            for (int mt = 0; mt < 2; ++mt) {
                #pragma unroll
                for (int r = 0; r < 4; ++r) {
                    int t = mt*16 + quad*4 + r;
                    size_t idx = (g0 + t) * CDIM + c;
                    y[idx] = y[idx] + acc[mt][j][r] + bias;
                }
            }
        }
    }
}

extern "C" void kernel_launch(void* const* d_in, const int* in_sizes, int n_in,
                              void* d_out, int out_size, void* d_ws, size_t ws_size,
                              hipStream_t stream) {
    (void)in_sizes; (void)n_in; (void)ws_size; (void)out_size;
    const float* x      = (const float*)d_in[0];
    const float* qkv_w  = (const float*)d_in[3];
    const float* qkv_b  = (const float*)d_in[4];
    const float* proj_w = (const float*)d_in[5];
    const float* proj_b = (const float*)d_in[6];
    const float* rpb    = (const float*)d_in[7];
    const float* n1w    = (const float*)d_in[8];
    const float* n1b    = (const float*)d_in[9];
    const float* n2w    = (const float*)d_in[10];
    const float* n2b    = (const float*)d_in[11];
    const float* w1     = (const float*)d_in[12];
    const float* b1     = (const float*)d_in[13];
    const float* w2     = (const float*)d_in[14];
    const float* b2     = (const float*)d_in[15];
    float* out = (float*)d_out;

    __bf16* w1t   = (__bf16*)d_ws;                       // 147456 * 2B
    __bf16* w2t   = (__bf16*)((char*)d_ws + 294912);     // 147456 * 2B
    __bf16* qkvt  = (__bf16*)((char*)d_ws + 589824);     // 110592 * 2B
    __bf16* projt = (__bf16*)((char*)d_ws + 811008);     //  36864 * 2B  (total 884736 B)

    prep_kernel<<<dim3(576), dim3(256), 0, stream>>>(qkv_w, proj_w, w1, w2, qkvt, projt, w1t, w2t);
    attn_kernel<<<dim3(8 * 1024), dim3(256), 0, stream>>>(
        x, qkvt, qkv_b, projt, proj_b, rpb, n1w, n1b, out);
    mlp_kernel<<<dim3(401408 / 32), dim3(256), 0, stream>>>(
        out, n2w, n2b, w1t, b1, w2t, b2);
}

// Round 2
// 3538.286 us; speedup vs baseline: 1.8434x; 1.0235x over previous
//
#include <hip/hip_runtime.h>
#include <hip/hip_bf16.h>

// Swin block, fixed shapes: B=8, H=W=224, C=192, WS=7, SHIFT=3, NH=6, HD=32, DFF=768
// prep:   transpose qkv_w/proj_w/w1/w2 to bf16 [n][k] layout in d_ws.
// attn:   one window per block, 4 waves = 4 M-tiles. LN1 + QKV + attn + proj + residual.
//         Barrier-minimized: 1 __syncthreads per head (K/V double-buffered, cross-wave);
//         Q/P/O stay wave-local via per-wave LDS scratch; LN output A-frags in registers;
//         rpb staged in LDS. All GEMMs mfma_f32_16x16x32_bf16, f32 accumulation.
// mlp:    32 tokens/block, LN2 + GEMM1 + GELU + GEMM2 + residual (unchanged).

#define CDIM 192
#define NH6 6
#define HD32 32
#define NTOK 49
#define HW224 224
#define LTOK 50176

typedef __bf16 bf16x8 __attribute__((ext_vector_type(8)));
typedef float  f32x4  __attribute__((ext_vector_type(4)));

__device__ __forceinline__ int region_id(int p) {
    return (p < 217) ? 0 : ((p < 221) ? 1 : 2);
}

#define XSTR 196          // xn row stride (bf16): 392 B -> bank-clean for A-frag reads
#define POOLB 28672       // phase-2: kh 10240 + vt 9216 + wls 9216 ( > xn 25088 )

__global__ __launch_bounds__(256) void attn_kernel(
    const float* __restrict__ x,
    const __bf16* __restrict__ qkvt, const float* __restrict__ qkv_b,
    const __bf16* __restrict__ projt, const float* __restrict__ proj_b,
    const float* __restrict__ rpb,
    const float* __restrict__ n1w, const float* __restrict__ n1b,
    float* __restrict__ y)
{
    __shared__ __attribute__((aligned(16))) char pool[POOLB];
    __shared__ float rpb_s[169 * NH6];
    __shared__ int regid[NTOK];

    // phase-1 view: LN output
    __bf16 (* const xn)[XSTR] = (__bf16 (*)[XSTR])pool;
    // phase-2 views (overlap xn; separated by barrier)
    __bf16 (* const kh)[64][40] = (__bf16 (*)[64][40])pool;             // 2 x 64 x 40 = 10240 B
    __bf16 (* const vt)[32][72] = (__bf16 (*)[32][72])(pool + 10240);   // 2 x 32 x 72 =  9216 B
    __bf16* const wlsbase       = (__bf16*)(pool + 19456);              // 4 x 16 x 72 =  9216 B

    const int tid = threadIdx.x;
    const int b  = blockIdx.x >> 10;
    const int w  = blockIdx.x & 1023;
    const int wr = w >> 5, wc = w & 31;
    const int wv = tid >> 6, lane = tid & 63;
    const int ln = lane & 15, quad = lane >> 4;

    __bf16 (* const wls)[72] = (__bf16 (*)[72])(wlsbase + wv * 16 * 72);

    if (tid < NTOK) {
        int r = tid / 7, cn = tid % 7;
        regid[tid] = region_id(wr*7 + r)*3 + region_id(wc*7 + cn);
    }
    for (int i = tid; i < 169 * NH6; i += 256) rpb_s[i] = rpb[i];

    // ---- LN1 -> xn (bf16); one wave per token ----
    for (int n = wv; n < NTOK; n += 4) {
        int r = n / 7, cn = n % 7;
        int hh = (wr*7 + r + 3) % HW224;
        int ww = (wc*7 + cn + 3) % HW224;
        const float* xp = x + ((size_t)b * LTOK + hh*HW224 + ww) * CDIM;
        float v0 = xp[lane], v1 = xp[lane+64], v2 = xp[lane+128];
        float s = v0+v1+v2, s2 = v0*v0+v1*v1+v2*v2;
        #pragma unroll
        for (int off = 32; off > 0; off >>= 1) {
            s  += __shfl_down(s, off);
            s2 += __shfl_down(s2, off);
        }
        s = __shfl(s, 0); s2 = __shfl(s2, 0);
        float mean = s * (1.0f/CDIM);
        float var  = s2 * (1.0f/CDIM) - mean*mean;
        float rstd = rsqrtf(var + 1e-5f);
        xn[n][lane]     = (__bf16)((v0-mean)*rstd*n1w[lane]     + n1b[lane]);
        xn[n][lane+64]  = (__bf16)((v1-mean)*rstd*n1w[lane+64]  + n1b[lane+64]);
        xn[n][lane+128] = (__bf16)((v2-mean)*rstd*n1w[lane+128] + n1b[lane+128]);
    }
    __syncthreads();

    // ---- A-fragments (head-independent, K=192) into registers; zero padding rows ----
    bf16x8 areg[6];
    {
        const int row = wv*16 + ln;
        #pragma unroll
        for (int ks = 0; ks < 6; ++ks)
            areg[ks] = *(const bf16x8*)&xn[row][ks*32 + quad*8];
        if (row >= NTOK) {
            #pragma unroll
            for (int ks = 0; ks < 6; ++ks)
                #pragma unroll
                for (int e = 0; e < 8; ++e) areg[ks][e] = (__bf16)0.0f;
        }
    }
    __syncthreads();   // xn dead; pool now owned by kh/vt/wls

    f32x4 pacc[12];
    #pragma unroll
    for (int j = 0; j < 12; ++j) pacc[j] = (f32x4){0.f,0.f,0.f,0.f};

    const float qscale = 0.17677669529663689f;
    const f32x4 z4 = (f32x4){0.f,0.f,0.f,0.f};

    for (int h = 0; h < NH6; ++h) {
        const int buf = h & 1;

        // ---- QKV GEMM: A = regs, B = qkvt (global/L2). N = 96 {q0,q1,k0,k1,v0,v1} ----
        f32x4 aq[6];
        #pragma unroll
        for (int j = 0; j < 6; ++j) aq[j] = z4;
        #pragma unroll
        for (int ks = 0; ks < 6; ++ks) {
            #pragma unroll
            for (int nt = 0; nt < 6; ++nt) {
                int wcol = (nt>>1)*192 + h*32 + (nt&1)*16 + ln;
                bf16x8 bb = *(const bf16x8*)(qkvt + (size_t)wcol*192 + ks*32 + quad*8);
                aq[nt] = __builtin_amdgcn_mfma_f32_16x16x32_bf16(areg[ks], bb, aq[nt], 0, 0, 0);
            }
        }
        // scatter: Q -> wave-local wls, K/V -> cross-wave double buffers
        #pragma unroll
        for (int nt = 0; nt < 6; ++nt) {
            int part = nt>>1, sub = nt&1;
            float bias = qkv_b[part*192 + h*32 + sub*16 + ln];
            #pragma unroll
            for (int r = 0; r < 4; ++r) {
                int lrow = quad*4 + r;
                int grow = wv*16 + lrow;
                float v = aq[nt][r] + bias;
                if (part == 0)      wls[lrow][sub*16+ln]       = (__bf16)(v*qscale);
                else if (part == 1) kh[buf][grow][sub*16+ln]   = (__bf16)v;
                else                vt[buf][sub*16+ln][grow]   = (__bf16)v;
            }
        }
        __syncthreads();   // the ONLY barrier per head: K/V[buf] ready for all waves

        // ---- S = Q.K^T (K=32), 4 N-tiles ----
        f32x4 sa[4];
        {
            bf16x8 qa = *(const bf16x8*)&wls[ln][quad*8];
            #pragma unroll
            for (int nt = 0; nt < 4; ++nt) {
                bf16x8 bb = *(const bf16x8*)&kh[buf][nt*16+ln][quad*8];
                sa[nt] = __builtin_amdgcn_mfma_f32_16x16x32_bf16(qa, bb, z4, 0, 0, 0);
            }
        }
        // ---- bias + mask + softmax, in place on sa (16-lane row groups) ----
        #pragma unroll
        for (int r = 0; r < 4; ++r) {
            int row = wv*16 + quad*4 + r;
            int rq = row < NTOK ? row : 0;
            int r7 = rq/7, rm7 = rq - r7*7;
            int rreg = regid[rq];
            float rowmax = -3.0e30f;
            #pragma unroll
            for (int nt = 0; nt < 4; ++nt) {
                int col = nt*16 + ln;
                int cc = col < NTOK ? col : 0;
                int c7 = cc/7, cm7 = cc - c7*7;
                float sv = sa[nt][r] + rpb_s[((r7-c7+6)*13 + (rm7-cm7+6))*NH6 + h];
                if (regid[cc] != rreg) sv -= 100.f;
                if (col >= NTOK) sv = -1.0e30f;
                sa[nt][r] = sv;
                rowmax = fmaxf(rowmax, sv);
            }
            #pragma unroll
            for (int m = 1; m < 16; m <<= 1) rowmax = fmaxf(rowmax, __shfl_xor(rowmax, m));
            float sum = 0.f;
            #pragma unroll
            for (int nt = 0; nt < 4; ++nt) {
                float e = __expf(sa[nt][r] - rowmax);
                sa[nt][r] = e; sum += e;
            }
            #pragma unroll
            for (int m = 1; m < 16; m <<= 1) sum += __shfl_xor(sum, m);
            float inv = 1.0f / sum;
            #pragma unroll
            for (int nt = 0; nt < 4; ++nt) sa[nt][r] *= inv;
        }
        // P -> wave-local wls (overwrites Q region; wave-internal order is safe)
        #pragma unroll
        for (int r = 0; r < 4; ++r) {
            int lrow = quad*4 + r;
            #pragma unroll
            for (int nt = 0; nt < 4; ++nt) wls[lrow][nt*16+ln] = (__bf16)sa[nt][r];
        }

        // ---- O = P.V (K=64 incl. zero padding cols) ----
        f32x4 ov[2];
        #pragma unroll
        for (int j = 0; j < 2; ++j) ov[j] = z4;
        #pragma unroll
        for (int ks = 0; ks < 2; ++ks) {
            bf16x8 pa = *(const bf16x8*)&wls[ln][ks*32 + quad*8];
            #pragma unroll
            for (int nt = 0; nt < 2; ++nt) {
                bf16x8 bb = *(const bf16x8*)&vt[buf][nt*16+ln][ks*32 + quad*8];
                ov[nt] = __builtin_amdgcn_mfma_f32_16x16x32_bf16(pa, bb, ov[nt], 0, 0, 0);
            }
        }
        // O -> wave-local wls (overwrites P cols 0..31 after PV reads)
        #pragma unroll
        for (int nt = 0; nt < 2; ++nt)
            #pragma unroll
            for (int r = 0; r < 4; ++r)
                wls[quad*4 + r][nt*16+ln] = (__bf16)ov[nt][r];

        // ---- proj partial GEMM (K=32 of this head); overlaps next head's QKV ----
        {
            bf16x8 oa = *(const bf16x8*)&wls[ln][quad*8];
            #pragma unroll
            for (int nt = 0; nt < 12; ++nt) {
                bf16x8 bb = *(const bf16x8*)(projt + (size_t)(nt*16+ln)*192 + h*32 + quad*8);
                pacc[nt] = __builtin_amdgcn_mfma_f32_16x16x32_bf16(oa, bb, pacc[nt], 0, 0, 0);
            }
        }
    }

    // ---- epilogue: y = x + proj + proj_b (rows >= 49 discarded) ----
    #pragma unroll
    for (int r = 0; r < 4; ++r) {
        int row = wv*16 + quad*4 + r;
        if (row < NTOK) {
            int hh = (wr*7 + row/7 + 3) % HW224;
            int ww = (wc*7 + row%7 + 3) % HW224;
            size_t base = ((size_t)b * LTOK + hh*HW224 + ww) * CDIM;
            #pragma unroll
            for (int nt = 0; nt < 12; ++nt) {
                int c = nt*16 + ln;
                y[base + c] = x[base + c] + pacc[nt][r] + proj_b[c];
            }
        }
    }
}

// ---- weight prep: all weights -> bf16 [n][k] transposed layouts in d_ws ----
__global__ __launch_bounds__(256) void prep_kernel(
    const float* __restrict__ qkv_w, const float* __restrict__ proj_w,
    const float* __restrict__ w1, const float* __restrict__ w2,
    __bf16* __restrict__ qkvt, __bf16* __restrict__ projt,
    __bf16* __restrict__ w1t, __bf16* __restrict__ w2t)
{
    int i = blockIdx.x * 256 + threadIdx.x;
    if (i < 192*768) {
        int k1 = i / 768, n1 = i % 768;
        w1t[n1*192 + k1] = (__bf16)w1[i];
        int k2 = i / 192, n2 = i % 192;
        w2t[n2*768 + k2] = (__bf16)w2[i];
    }
    if (i < 192*576) {
        int k = i / 576, n = i % 576;
        qkvt[n*192 + k] = (__bf16)qkv_w[i];
    }
    if (i < 192*192) {
        int k = i / 192, n = i % 192;
        projt[n*192 + k] = (__bf16)proj_w[i];
    }
}

// ---- MLP: 32 tokens/block, MFMA bf16 16x16x32 (unchanged) ----
#define XPAD 200   // 192+8: row stride 400B -> 2-way LDS alias (free)
#define HPAD 776   // 768+8: row stride 1552B -> 2-way LDS alias (free)

__global__ __launch_bounds__(256) void mlp_kernel(
    float* __restrict__ y,
    const float* __restrict__ n2w, const float* __restrict__ n2b,
    const __bf16* __restrict__ w1t, const float* __restrict__ b1,
    const __bf16* __restrict__ w2t, const float* __restrict__ b2)
{
    __shared__ __attribute__((aligned(16))) __bf16 xnb[32][XPAD];  // 12,800 B
    __shared__ __attribute__((aligned(16))) __bf16 hid[32][HPAD];  // 49,664 B (total 62,464)

    const int tid = threadIdx.x;
    const int wv = tid >> 6, lane = tid & 63;
    const int ln = lane & 15, quad = lane >> 4;
    const size_t g0 = (size_t)blockIdx.x * 32;

    // ---- LN2: one wave per token ----
    for (int t = wv; t < 32; t += 4) {
        const float* xp = y + (g0 + t) * CDIM;
        float v0 = xp[lane], v1 = xp[lane+64], v2 = xp[lane+128];
        float s = v0+v1+v2, s2 = v0*v0+v1*v1+v2*v2;
        #pragma unroll
        for (int off = 32; off > 0; off >>= 1) {
            s  += __shfl_down(s, off);
            s2 += __shfl_down(s2, off);
        }
        s = __shfl(s, 0); s2 = __shfl(s2, 0);
        float mean = s * (1.0f/CDIM);
        float var  = s2 * (1.0f/CDIM) - mean*mean;
        float rstd = rsqrtf(var + 1e-5f);
        xnb[t][lane]     = (__bf16)((v0-mean)*rstd*n2w[lane]     + n2b[lane]);
        xnb[t][lane+64]  = (__bf16)((v1-mean)*rstd*n2w[lane+64]  + n2b[lane+64]);
        xnb[t][lane+128] = (__bf16)((v2-mean)*rstd*n2w[lane+128] + n2b[lane+128]);
    }
    __syncthreads();

    // ---- GEMM1 + GELU -> hid ----
    {
        f32x4 acc[2][12];
        #pragma unroll
        for (int mt = 0; mt < 2; ++mt)
            #pragma unroll
            for (int j = 0; j < 12; ++j) acc[mt][j] = (f32x4){0.f,0.f,0.f,0.f};

        for (int ks = 0; ks < 6; ++ks) {           // K = 6 * 32
            const int kb = ks*32 + quad*8;
            bf16x8 a0 = *(const bf16x8*)&xnb[ln][kb];
            bf16x8 a1 = *(const bf16x8*)&xnb[16+ln][kb];
            #pragma unroll
            for (int j = 0; j < 12; ++j) {
                const int nt = wv*12 + j;
                bf16x8 bfr = *(const bf16x8*)(w1t + (size_t)(nt*16 + ln)*192 + kb);
                acc[0][j] = __builtin_amdgcn_mfma_f32_16x16x32_bf16(a0, bfr, acc[0][j], 0, 0, 0);
                acc[1][j] = __builtin_amdgcn_mfma_f32_16x16x32_bf16(a1, bfr, acc[1][j], 0, 0, 0);
            }
        }
        #pragma unroll
        for (int j = 0; j < 12; ++j) {
            const int c = (wv*12 + j)*16 + ln;
            const float bias = b1[c];
            #pragma unroll
            for (int mt = 0; mt < 2; ++mt) {
                #pragma unroll
                for (int r = 0; r < 4; ++r) {
                    int t = mt*16 + quad*4 + r;
                    float v = acc[mt][j][r] + bias;
                    hid[t][c] = (__bf16)(0.5f*v*(1.0f + erff(v*0.70710678118654752f)));
                }
            }
        }
    }
    __syncthreads();

    // ---- GEMM2 + residual ----
    {
        f32x4 acc[2][3];
        #pragma unroll
        for (int mt = 0; mt < 2; ++mt)
            #pragma unroll
            for (int j = 0; j < 3; ++j) acc[mt][j] = (f32x4){0.f,0.f,0.f,0.f};

        for (int ks = 0; ks < 24; ++ks) {          // K = 24 * 32
            const int kb = ks*32 + quad*8;
            bf16x8 a0 = *(const bf16x8*)&hid[ln][kb];
            bf16x8 a1 = *(const bf16x8*)&hid[16+ln][kb];
            #pragma unroll
            for (int j = 0; j < 3; ++j) {
                const int nt = wv*3 + j;
                bf16x8 bfr = *(const bf16x8*)(w2t + (size_t)(nt*16 + ln)*768 + kb);
                acc[0][j] = __builtin_amdgcn_mfma_f32_16x16x32_bf16(a0, bfr, acc[0][j], 0, 0, 0);
                acc[1][j] = __builtin_amdgcn_mfma_f32_16x16x32_bf16(a1, bfr, acc[1][j], 0, 0, 0);
            }
        }
        #pragma unroll
        for (int j = 0; j < 3; ++j) {
            const int c = (wv*3 + j)*16 + ln;
            const float bias = b2[c];
            #pragma unroll
            for (int mt = 0; mt < 2; ++mt) {
                #pragma unroll
                for (int r = 0; r < 4; ++r) {
                    int t = mt*16 + quad*4 + r;
                    size_t idx = (g0 + t) * CDIM + c;
                    y[idx] = y[idx] + acc[mt][j][r] + bias;
                }
            }
        }
    }
}

extern "C" void kernel_launch(void* const* d_in, const int* in_sizes, int n_in,
                              void* d_out, int out_size, void* d_ws, size_t ws_size,
                              hipStream_t stream) {
    (void)in_sizes; (void)n_in; (void)ws_size; (void)out_size;
    const float* x      = (const float*)d_in[0];
    const float* qkv_w  = (const float*)d_in[3];
    const float* qkv_b  = (const float*)d_in[4];
    const float* proj_w = (const float*)d_in[5];
    const float* proj_b = (const float*)d_in[6];
    const float* rpb    = (const float*)d_in[7];
    const float* n1w    = (const float*)d_in[8];
    const float* n1b    = (const float*)d_in[9];
    const float* n2w    = (const float*)d_in[10];
    const float* n2b    = (const float*)d_in[11];
    const float* w1     = (const float*)d_in[12];
    const float* b1     = (const float*)d_in[13];
    const float* w2     = (const float*)d_in[14];
    const float* b2     = (const float*)d_in[15];
    float* out = (float*)d_out;

    __bf16* w1t   = (__bf16*)d_ws;                       // 147456 * 2B
    __bf16* w2t   = (__bf16*)((char*)d_ws + 294912);     // 147456 * 2B
    __bf16* qkvt  = (__bf16*)((char*)d_ws + 589824);     // 110592 * 2B
    __bf16* projt = (__bf16*)((char*)d_ws + 811008);     //  36864 * 2B  (total 884736 B)

    prep_kernel<<<dim3(576), dim3(256), 0, stream>>>(qkv_w, proj_w, w1, w2, qkvt, projt, w1t, w2t);
    attn_kernel<<<dim3(8 * 1024), dim3(256), 0, stream>>>(
        x, qkvt, qkv_b, projt, proj_b, rpb, n1w, n1b, out);
    mlp_kernel<<<dim3(401408 / 32), dim3(256), 0, stream>>>(
        out, n2w, n2b, w1t, b1, w2t, b2);
}